// Round 13
// baseline (80.824 us; speedup 1.0000x reference)
//
#include <hip/hip_runtime.h>
#include <hip/hip_bf16.h>

// Locally-connected 2D: out[b,o,y,x] = sum_{c,kh,kw} x[b,c,y+kh,x+kw] * W[y,x,o,c*25+kh*5+kw] + b[y,x,o]
// x: [128,3,64,64] f32, W: [60,60,32,75] f32, bias: [60,60,32] f32, out: [128,32,60,60] f32.
//
// Two kernels:
// 1) wpack: W (+bias) -> Wp[pos][o][128] bf16 in EXACT MFMA B-fragment order:
//    k' = cm*8 + w (cm = c*5+kh), window slots [xi, xi+5) hold W (xi = pos%4 shift,
//    applied via wave-uniform 128-bit funnel shift), others 0; slot 120 = bias
//    (consumed by one-hot A[b][120]=1). Staged via async global_load_lds.
//    ROUND-13 FIX: store loop must emit ALL 8 uint4s (32 dwords = 64 slots);
//    r11 had q<4 stride 16 (wrong slots), r12 had q<4 stride 8 (groups 4-7 never
//    stored -> stale poison). Correct: q<8, stride 8.
// 2) lc2d_main: NO LDS, NO barrier, NO cvt for B. Block = (b-slice of 32, one 64B
//    output line = 16 flattened positions = 4 groups of 4 x). Wave = 16x16 (b,o)
//    tile; per group 8 A-loads + 16 coalesced B-loads + 16 MFMA -> 64-VGPR line
//    buffer; store = 4 consecutive dwordx4 per (b,o) row = full-line writes.

#define RY 60
#define RX 60
#define OC 32
#define BATCH 128
#define CIN 3
#define HW 64
#define NPOS 3600
#define KPACK 128

typedef __attribute__((ext_vector_type(8))) short short8;
typedef __attribute__((ext_vector_type(4))) float f32x4;
typedef unsigned long long ull;

__device__ __forceinline__ ushort bf16u(float f) {
    __hip_bfloat16 h = __float2bfloat16(f);
    return *reinterpret_cast<ushort*>(&h);
}
__device__ __forceinline__ unsigned pk2(float a, float b) {
    return (unsigned)bf16u(a) | ((unsigned)bf16u(b) << 16);
}
__device__ __forceinline__ int swz900(int id) {   // bijective XCD chunking for 900
    const int xcd = id & 7, ii = id >> 3;
    return (xcd < 4 ? xcd * 113 : 452 + (xcd - 4) * 112) + ii;
}

// ---------------- prepass: W + bias -> packed bf16 fragments ----------------
__global__ __launch_bounds__(256, 4) void lc2d_wpack(
    const float* __restrict__ w, const float* __restrict__ bias,
    ushort* __restrict__ wp)
{
    __shared__ __align__(16) float wlds[9600 + 128];   // 4 positions x 2400 f32

    const int G   = swz900(blockIdx.x);
    const int tid = threadIdx.x;
    const int lane = tid & 63, wid = tid >> 6;

    // async DMA: 38.4KB contiguous W for positions 4G..4G+4 (38 x 1KB chunks)
    {
        const float* gW = w + (size_t)G * 4 * (OC * 75);
        for (int j = wid; j < 38; j += 4) {
            const int chunk0 = j * 64;
            int ci = chunk0 + lane;
            if (ci > 2399) ci = 2399;                  // 16B-aligned clamp
            __builtin_amdgcn_global_load_lds(
                (const __attribute__((address_space(1))) unsigned*)(gW + ci * 4),
                (__attribute__((address_space(3))) unsigned*)&wlds[chunk0 * 4],
                16, 0, 0);
        }
    }

    // thread = (xi, o, half): xi wave-uniform (tid>>6)
    const int xi = tid >> 6, o = (tid >> 1) & 31, half = tid & 1;
    const float bv = bias[(size_t)(G * 4 + xi) * OC + o];   // issue early
    __syncthreads();

    const float* src = &wlds[xi * 2400 + o * 75];
    const int s = xi * 16;                 // wave-uniform shift (bits)
    unsigned wd[32];
    #pragma unroll
    for (int i = 0; i < 32; ++i) wd[i] = 0u;

    #pragma unroll
    for (int cc = 0; cc < 8; ++cc) {
        const int cm = half * 8 + cc;
        if (cm < 15) {
            const float* sp = src + cm * 5;
            const ushort h0 = bf16u(sp[0]), h1 = bf16u(sp[1]), h2 = bf16u(sp[2]),
                         h3 = bf16u(sp[3]), h4 = bf16u(sp[4]);
            const ull lo = (ull)h0 | ((ull)h1 << 16) | ((ull)h2 << 32) | ((ull)h3 << 48);
            const ull hi = (ull)h4;
            const ull rlo = lo << s;
            const ull rhi = (hi << s) | (s ? (lo >> (64 - s)) : 0ull);
            wd[cc * 4 + 0] = (unsigned)rlo;
            wd[cc * 4 + 1] = (unsigned)(rlo >> 32);
            wd[cc * 4 + 2] = (unsigned)rhi;
            wd[cc * 4 + 3] = (unsigned)(rhi >> 32);
        } else {
            wd[cc * 4 + 0] = (unsigned)bf16u(bv);      // k'=120 slot0 = bias
        }
    }
    ushort* dst = wp + ((size_t)(G * 4 + xi) * OC + o) * KPACK + half * 64;
    #pragma unroll
    for (int q = 0; q < 8; ++q)                        // FIX: all 8 groups, stride 8
        *reinterpret_cast<uint4*>(dst + q * 8) =
            make_uint4(wd[q * 4], wd[q * 4 + 1], wd[q * 4 + 2], wd[q * 4 + 3]);
}

// ---------------- main: fused GEMM + full-line stores ----------------
__global__ __launch_bounds__(256, 2) void lc2d_main(
    const float* __restrict__ x, const ushort* __restrict__ wp,
    float* __restrict__ out)
{
    const int lin = swz900(blockIdx.x);
    const int bs = lin & 3;            // b-slice (siblings adjacent -> share Wp in L2)
    const int q  = lin >> 2;           // output line index [0,225)

    const int lane = threadIdx.x & 63, wid = threadIdx.x >> 6;
    const int lrow = lane & 15, lgrp = lane >> 4;
    const int mt = wid >> 1, nt = wid & 1;
    const int bbase = bs * 32 + mt * 16;
    const int o = nt * 16 + lrow;      // this lane's output channel (D col)
    const int b = bbase + lrow;        // this lane's A row

    f32x4 linebuf[4][4];               // [j][r] -> 64 VGPR

    #pragma unroll
    for (int j = 0; j < 4; ++j) {
        const int G   = q * 4 + j;
        const int y   = G / 15;
        const int x0  = (G - y * 15) * 4;

        // A fragments: 8-float windows, direct from global; cm==15 -> one-hot 1.0
        short8 af[4];
        #pragma unroll
        for (int ks = 0; ks < 4; ++ks) {
            const int cm = ks * 4 + lgrp;
            union { unsigned u[4]; short8 s8; } cv;
            if (cm < 15) {
                const int c = cm / 5, kh = cm - c * 5;
                const float* src = x + (size_t)((b * CIN + c) * HW + (y + kh)) * HW + x0;
                const float4 v0 = *(const float4*)(src);
                const float4 v1 = *(const float4*)(src + 4);
                cv.u[0] = pk2(v0.x, v0.y); cv.u[1] = pk2(v0.z, v0.w);
                cv.u[2] = pk2(v1.x, v1.y); cv.u[3] = pk2(v1.z, v1.w);
            } else {
                cv.u[0] = 0x3f80u; cv.u[1] = 0u; cv.u[2] = 0u; cv.u[3] = 0u;  // bf16 1.0 @ k'=120
            }
            af[ks] = cv.s8;
        }

        f32x4 accx[4];
        #pragma unroll
        for (int xi = 0; xi < 4; ++xi) accx[xi] = (f32x4){0.f, 0.f, 0.f, 0.f};

        #pragma unroll
        for (int xi = 0; xi < 4; ++xi) {
            const ushort* wb = wp + ((size_t)(4 * G + xi) * OC + o) * KPACK + lgrp * 8;
            #pragma unroll
            for (int ks = 0; ks < 4; ++ks) {
                const short8 bf = *(const short8*)(wb + ks * 32);
                accx[xi] = __builtin_amdgcn_mfma_f32_16x16x32_bf16(af[ks], bf, accx[xi], 0, 0, 0);
            }
        }

        #pragma unroll
        for (int r = 0; r < 4; ++r)
            linebuf[j][r] = (f32x4){accx[0][r], accx[1][r], accx[2][r], accx[3][r]};
    }

    // store: per (b,o) row, 4 consecutive dwordx4 = one full 64B line
    const int bg0 = bbase + lgrp * 4;
    #pragma unroll
    for (int r = 0; r < 4; ++r) {
        float* ob = out + (size_t)((bg0 + r) * OC + o) * NPOS + 16 * q;
        #pragma unroll
        for (int j = 0; j < 4; ++j)
            *reinterpret_cast<f32x4*>(ob + 4 * j) = linebuf[j][r];
    }
}

// ---------------- fallback (round-10 fused, no workspace) ----------------
__global__ __launch_bounds__(256, 4) void lc2d_fb(
    const float* __restrict__ x, const float* __restrict__ w,
    const float* __restrict__ bias, float* __restrict__ out)
{
    __shared__ __align__(16) float wlds[4 * 2400 + 128];
    const int tid = threadIdx.x;
    const int id  = blockIdx.x;
    const int lin = (id & 7) * 450 + (id >> 3);
    const int bs  = lin & 3;
    const int pg  = lin >> 2;
    const int y   = pg / 15;
    const int x0  = (pg - y * 15) * 4;
    const int pos0 = y * RX + x0;
    const int lane = tid & 63, wid = tid >> 6;
    const int lrow = lane & 15, lgrp = lane >> 4;
    const int mt = wid >> 1, nt = wid & 1;
    const int bbase = bs * 32 + mt * 16;
    const int o = nt * 16 + lrow;

    float4 av[4][2];
    #pragma unroll
    for (int ks = 0; ks < 4; ++ks) {
        const int cm = ks * 4 + lgrp;
        if (cm < 15) {
            const int c = cm / 5, kh = cm - c * 5;
            const int b = bbase + lrow;
            const float* src = x + (size_t)((b * CIN + c) * HW + (y + kh)) * HW + x0;
            av[ks][0] = *(const float4*)(src);
            av[ks][1] = *(const float4*)(src + 4);
        }
    }
    {
        const float* gW = w + (size_t)pos0 * 2400;
        for (int j = wid; j < 38; j += 4) {
            const int chunk0 = j * 64;
            int ci = chunk0 + lane;
            if (ci > 2399) ci = 2399;
            __builtin_amdgcn_global_load_lds(
                (const __attribute__((address_space(1))) unsigned*)(gW + ci * 4),
                (__attribute__((address_space(3))) unsigned*)&wlds[chunk0 * 4],
                16, 0, 0);
        }
    }
    float bv[4];
    #pragma unroll
    for (int xi = 0; xi < 4; ++xi) bv[xi] = bias[(size_t)(pos0 + xi) * OC + o];

    short8 af[4];
    #pragma unroll
    for (int ks = 0; ks < 4; ++ks) {
        const int cm = ks * 4 + lgrp;
        union { unsigned u[4]; short8 s8; } cv;
        if (cm < 15) {
            cv.u[0] = pk2(av[ks][0].x, av[ks][0].y); cv.u[1] = pk2(av[ks][0].z, av[ks][0].w);
            cv.u[2] = pk2(av[ks][1].x, av[ks][1].y); cv.u[3] = pk2(av[ks][1].z, av[ks][1].w);
        } else { cv.u[0] = cv.u[1] = cv.u[2] = cv.u[3] = 0u; }
        af[ks] = cv.s8;
    }
    __syncthreads();

    f32x4 accx[4];
    #pragma unroll
    for (int xi = 0; xi < 4; ++xi) accx[xi] = (f32x4){0.f, 0.f, 0.f, 0.f};
    const int wbase = o * 75;
    #pragma unroll
    for (int ks = 0; ks < 4; ++ks) {
        const int cm = ks * 4 + lgrp;
        const int soff = wbase + cm * 5;
        #pragma unroll
        for (int xi = 0; xi < 4; ++xi) {
            const float* s = &wlds[xi * 2400 + soff];
            const ushort h[5] = {bf16u(s[0]), bf16u(s[1]), bf16u(s[2]), bf16u(s[3]), bf16u(s[4])};
            unsigned wd[4] = {0u, 0u, 0u, 0u};
            #pragma unroll
            for (int kw = 0; kw < 5; ++kw) {
                const int ws = xi + kw;
                wd[ws >> 1] |= (unsigned)h[kw] << ((ws & 1) * 16);
            }
            union { unsigned u[4]; short8 s8; } cv;
            cv.u[0] = wd[0]; cv.u[1] = wd[1]; cv.u[2] = wd[2]; cv.u[3] = wd[3];
            accx[xi] = __builtin_amdgcn_mfma_f32_16x16x32_bf16(af[ks], cv.s8, accx[xi], 0, 0, 0);
        }
    }
    #pragma unroll
    for (int r = 0; r < 4; ++r) {
        const int bg = bbase + lgrp * 4 + r;
        float4 v;
        v.x = accx[0][r] + bv[0]; v.y = accx[1][r] + bv[1];
        v.z = accx[2][r] + bv[2]; v.w = accx[3][r] + bv[3];
        *(float4*)(out + (size_t)(bg * OC + o) * (RY * RX) + pos0) = v;
    }
}

extern "C" void kernel_launch(void* const* d_in, const int* in_sizes, int n_in,
                              void* d_out, int out_size, void* d_ws, size_t ws_size,
                              hipStream_t stream) {
    const float* x    = (const float*)d_in[0];
    const float* w    = (const float*)d_in[1];
    const float* bias = (const float*)d_in[2];
    float* out        = (float*)d_out;

    const size_t wp_bytes = (size_t)NPOS * OC * KPACK * sizeof(ushort);  // 29.5 MB
    if (ws_size >= wp_bytes) {
        ushort* wp = (ushort*)d_ws;
        lc2d_wpack<<<900, 256, 0, stream>>>(w, bias, wp);
        lc2d_main<<<900, 256, 0, stream>>>(x, wp, out);
    } else {
        lc2d_fb<<<3600, 256, 0, stream>>>(x, w, bias, out);
    }
}

// Round 14
// 76.333 us; speedup vs baseline: 1.0588x; 1.0588x over previous
//
#include <hip/hip_runtime.h>
#include <hip/hip_bf16.h>

// Locally-connected 2D: out[b,o,y,x] = sum_{c,kh,kw} x[b,c,y+kh,x+kw] * W[y,x,o,c*25+kh*5+kw] + b[y,x,o]
// x: [128,3,64,64] f32, W: [60,60,32,75] f32, bias: [60,60,32] f32, out: [128,32,60,60] f32.
//
// 1) wpack (verified r13): W (+bias) -> Wp[pos][o][128] bf16 in EXACT MFMA B-fragment
//    order: k' = cm*8 + w (cm=c*5+kh), window [xi,xi+5) holds W (xi=pos%4 baked via
//    funnel shift), slot 120 = bias (consumed by one-hot A=1.0).
// 2) main v2 (r14): pure-ILP, no LDS, no barrier, no serial loops. Block = (bs,G):
//    3600 blocks, 4 waves. Each lane issues ALL 30 loads up front (14 A f32x4 +
//    16 B short8, MFMA-ready), packs A during load returns, 16 MFMA, 4 float4 stores.
//    Mapping lin=(id&7)*450+(id>>3), bs fastest -> Wp-sharing siblings + line-partner
//    G's adjacent on one XCD (L2 reuse + store merge).

#define RY 60
#define RX 60
#define OC 32
#define BATCH 128
#define CIN 3
#define HW 64
#define NPOS 3600
#define KPACK 128

typedef __attribute__((ext_vector_type(8))) short short8;
typedef __attribute__((ext_vector_type(4))) float f32x4;
typedef unsigned long long ull;

__device__ __forceinline__ ushort bf16u(float f) {
    __hip_bfloat16 h = __float2bfloat16(f);
    return *reinterpret_cast<ushort*>(&h);
}
__device__ __forceinline__ unsigned pk2(float a, float b) {
    return (unsigned)bf16u(a) | ((unsigned)bf16u(b) << 16);
}
__device__ __forceinline__ int swz900(int id) {   // bijective XCD chunking for 900
    const int xcd = id & 7, ii = id >> 3;
    return (xcd < 4 ? xcd * 113 : 452 + (xcd - 4) * 112) + ii;
}

// ---------------- prepass: W + bias -> packed bf16 fragments ----------------
__global__ __launch_bounds__(256, 4) void lc2d_wpack(
    const float* __restrict__ w, const float* __restrict__ bias,
    ushort* __restrict__ wp)
{
    __shared__ __align__(16) float wlds[9600 + 128];   // 4 positions x 2400 f32

    const int G   = swz900(blockIdx.x);
    const int tid = threadIdx.x;
    const int lane = tid & 63, wid = tid >> 6;

    {   // async DMA: 38.4KB contiguous W for positions 4G..4G+4
        const float* gW = w + (size_t)G * 4 * (OC * 75);
        for (int j = wid; j < 38; j += 4) {
            const int chunk0 = j * 64;
            int ci = chunk0 + lane;
            if (ci > 2399) ci = 2399;
            __builtin_amdgcn_global_load_lds(
                (const __attribute__((address_space(1))) unsigned*)(gW + ci * 4),
                (__attribute__((address_space(3))) unsigned*)&wlds[chunk0 * 4],
                16, 0, 0);
        }
    }

    const int xi = tid >> 6, o = (tid >> 1) & 31, half = tid & 1;
    const float bv = bias[(size_t)(G * 4 + xi) * OC + o];
    __syncthreads();

    const float* src = &wlds[xi * 2400 + o * 75];
    const int s = xi * 16;
    unsigned wd[32];
    #pragma unroll
    for (int i = 0; i < 32; ++i) wd[i] = 0u;

    #pragma unroll
    for (int cc = 0; cc < 8; ++cc) {
        const int cm = half * 8 + cc;
        if (cm < 15) {
            const float* sp = src + cm * 5;
            const ushort h0 = bf16u(sp[0]), h1 = bf16u(sp[1]), h2 = bf16u(sp[2]),
                         h3 = bf16u(sp[3]), h4 = bf16u(sp[4]);
            const ull lo = (ull)h0 | ((ull)h1 << 16) | ((ull)h2 << 32) | ((ull)h3 << 48);
            const ull hi = (ull)h4;
            const ull rlo = lo << s;
            const ull rhi = (hi << s) | (s ? (lo >> (64 - s)) : 0ull);
            wd[cc * 4 + 0] = (unsigned)rlo;
            wd[cc * 4 + 1] = (unsigned)(rlo >> 32);
            wd[cc * 4 + 2] = (unsigned)rhi;
            wd[cc * 4 + 3] = (unsigned)(rhi >> 32);
        } else {
            wd[cc * 4 + 0] = (unsigned)bf16u(bv);      // k'=120 slot = bias
        }
    }
    ushort* dst = wp + ((size_t)(G * 4 + xi) * OC + o) * KPACK + half * 64;
    #pragma unroll
    for (int q = 0; q < 8; ++q)
        *reinterpret_cast<uint4*>(dst + q * 8) =
            make_uint4(wd[q * 4], wd[q * 4 + 1], wd[q * 4 + 2], wd[q * 4 + 3]);
}

// ---------------- main v2: pure-ILP fused GEMM ----------------
__global__ __launch_bounds__(256, 3) void lc2d_main(
    const float* __restrict__ x, const ushort* __restrict__ wp,
    float* __restrict__ out)
{
    const int id  = blockIdx.x;
    const int lin = (id & 7) * 450 + (id >> 3);   // same-XCD runs; bs fastest
    const int bs  = lin & 3;
    const int G   = lin >> 2;                     // [0,900)
    const int y   = G / 15;
    const int x0  = (G - y * 15) * 4;
    const int pos0 = y * RX + x0;                 // %4 == 0 -> 16B-aligned stores

    const int lane = threadIdx.x & 63, wid = threadIdx.x >> 6;
    const int lrow = lane & 15, lgrp = lane >> 4;
    const int mt = wid >> 1, nt = wid & 1;
    const int bbase = bs * 32 + mt * 16;
    const int o = nt * 16 + lrow;
    const int b = bbase + lrow;

    // ---- issue ALL A loads (14 independent f32x4) ----
    float4 av[4][2];
    #pragma unroll
    for (int ks = 0; ks < 4; ++ks) {
        const int cm = ks * 4 + lgrp;
        if (cm < 15) {
            const int c = cm / 5, kh = cm - c * 5;
            const float* src = x + (size_t)((b * CIN + c) * HW + (y + kh)) * HW + x0;
            av[ks][0] = *(const float4*)(src);
            av[ks][1] = *(const float4*)(src + 4);
        }
    }
    // ---- issue ALL B loads (16 independent short8, MFMA-ready) ----
    short8 bfr[4][4];   // [xi][ks]
    #pragma unroll
    for (int xi = 0; xi < 4; ++xi) {
        const ushort* wb = wp + ((size_t)(4 * G + xi) * OC + o) * KPACK + lgrp * 8;
        #pragma unroll
        for (int ks = 0; ks < 4; ++ks)
            bfr[xi][ks] = *(const short8*)(wb + ks * 32);
    }

    // ---- pack A (VALU overlaps load returns); cm==15 -> one-hot 1.0 @ k'=120 ----
    short8 af[4];
    #pragma unroll
    for (int ks = 0; ks < 4; ++ks) {
        const int cm = ks * 4 + lgrp;
        union { unsigned u[4]; short8 s8; } cv;
        if (cm < 15) {
            cv.u[0] = pk2(av[ks][0].x, av[ks][0].y); cv.u[1] = pk2(av[ks][0].z, av[ks][0].w);
            cv.u[2] = pk2(av[ks][1].x, av[ks][1].y); cv.u[3] = pk2(av[ks][1].z, av[ks][1].w);
        } else {
            cv.u[0] = 0x3f80u; cv.u[1] = 0u; cv.u[2] = 0u; cv.u[3] = 0u;
        }
        af[ks] = cv.s8;
    }

    // ---- 16 MFMA ----
    f32x4 accx[4];
    #pragma unroll
    for (int xi = 0; xi < 4; ++xi) accx[xi] = (f32x4){0.f, 0.f, 0.f, 0.f};
    #pragma unroll
    for (int xi = 0; xi < 4; ++xi)
        #pragma unroll
        for (int ks = 0; ks < 4; ++ks)
            accx[xi] = __builtin_amdgcn_mfma_f32_16x16x32_bf16(af[ks], bfr[xi][ks], accx[xi], 0, 0, 0);

    // ---- store: per (b,o) one aligned float4 of the 4 consecutive x ----
    #pragma unroll
    for (int r = 0; r < 4; ++r) {
        const int bg = bbase + lgrp * 4 + r;
        f32x4 v = (f32x4){accx[0][r], accx[1][r], accx[2][r], accx[3][r]};
        *reinterpret_cast<f32x4*>(out + (size_t)(bg * OC + o) * NPOS + pos0) = v;
    }
}

// ---------------- fallback (round-10 fused, no workspace) ----------------
__global__ __launch_bounds__(256, 4) void lc2d_fb(
    const float* __restrict__ x, const float* __restrict__ w,
    const float* __restrict__ bias, float* __restrict__ out)
{
    __shared__ __align__(16) float wlds[4 * 2400 + 128];
    const int tid = threadIdx.x;
    const int id  = blockIdx.x;
    const int lin = (id & 7) * 450 + (id >> 3);
    const int bs  = lin & 3;
    const int pg  = lin >> 2;
    const int y   = pg / 15;
    const int x0  = (pg - y * 15) * 4;
    const int pos0 = y * RX + x0;
    const int lane = tid & 63, wid = tid >> 6;
    const int lrow = lane & 15, lgrp = lane >> 4;
    const int mt = wid >> 1, nt = wid & 1;
    const int bbase = bs * 32 + mt * 16;
    const int o = nt * 16 + lrow;

    float4 av[4][2];
    #pragma unroll
    for (int ks = 0; ks < 4; ++ks) {
        const int cm = ks * 4 + lgrp;
        if (cm < 15) {
            const int c = cm / 5, kh = cm - c * 5;
            const int b = bbase + lrow;
            const float* src = x + (size_t)((b * CIN + c) * HW + (y + kh)) * HW + x0;
            av[ks][0] = *(const float4*)(src);
            av[ks][1] = *(const float4*)(src + 4);
        }
    }
    {
        const float* gW = w + (size_t)pos0 * 2400;
        for (int j = wid; j < 38; j += 4) {
            const int chunk0 = j * 64;
            int ci = chunk0 + lane;
            if (ci > 2399) ci = 2399;
            __builtin_amdgcn_global_load_lds(
                (const __attribute__((address_space(1))) unsigned*)(gW + ci * 4),
                (__attribute__((address_space(3))) unsigned*)&wlds[chunk0 * 4],
                16, 0, 0);
        }
    }
    float bv[4];
    #pragma unroll
    for (int xi = 0; xi < 4; ++xi) bv[xi] = bias[(size_t)(pos0 + xi) * OC + o];

    short8 af[4];
    #pragma unroll
    for (int ks = 0; ks < 4; ++ks) {
        const int cm = ks * 4 + lgrp;
        union { unsigned u[4]; short8 s8; } cv;
        if (cm < 15) {
            cv.u[0] = pk2(av[ks][0].x, av[ks][0].y); cv.u[1] = pk2(av[ks][0].z, av[ks][0].w);
            cv.u[2] = pk2(av[ks][1].x, av[ks][1].y); cv.u[3] = pk2(av[ks][1].z, av[ks][1].w);
        } else { cv.u[0] = cv.u[1] = cv.u[2] = cv.u[3] = 0u; }
        af[ks] = cv.s8;
    }
    __syncthreads();

    f32x4 accx[4];
    #pragma unroll
    for (int xi = 0; xi < 4; ++xi) accx[xi] = (f32x4){0.f, 0.f, 0.f, 0.f};
    const int wbase = o * 75;
    #pragma unroll
    for (int ks = 0; ks < 4; ++ks) {
        const int cm = ks * 4 + lgrp;
        const int soff = wbase + cm * 5;
        #pragma unroll
        for (int xi = 0; xi < 4; ++xi) {
            const float* s = &wlds[xi * 2400 + soff];
            const ushort h[5] = {bf16u(s[0]), bf16u(s[1]), bf16u(s[2]), bf16u(s[3]), bf16u(s[4])};
            unsigned wd[4] = {0u, 0u, 0u, 0u};
            #pragma unroll
            for (int kw = 0; kw < 5; ++kw) {
                const int ws = xi + kw;
                wd[ws >> 1] |= (unsigned)h[kw] << ((ws & 1) * 16);
            }
            union { unsigned u[4]; short8 s8; } cv;
            cv.u[0] = wd[0]; cv.u[1] = wd[1]; cv.u[2] = wd[2]; cv.u[3] = wd[3];
            accx[xi] = __builtin_amdgcn_mfma_f32_16x16x32_bf16(af[ks], cv.s8, accx[xi], 0, 0, 0);
        }
    }
    #pragma unroll
    for (int r = 0; r < 4; ++r) {
        const int bg = bbase + lgrp * 4 + r;
        float4 v;
        v.x = accx[0][r] + bv[0]; v.y = accx[1][r] + bv[1];
        v.z = accx[2][r] + bv[2]; v.w = accx[3][r] + bv[3];
        *(float4*)(out + (size_t)(bg * OC + o) * (RY * RX) + pos0) = v;
    }
}

extern "C" void kernel_launch(void* const* d_in, const int* in_sizes, int n_in,
                              void* d_out, int out_size, void* d_ws, size_t ws_size,
                              hipStream_t stream) {
    const float* x    = (const float*)d_in[0];
    const float* w    = (const float*)d_in[1];
    const float* bias = (const float*)d_in[2];
    float* out        = (float*)d_out;

    const size_t wp_bytes = (size_t)NPOS * OC * KPACK * sizeof(ushort);  // 29.5 MB
    if (ws_size >= wp_bytes) {
        ushort* wp = (ushort*)d_ws;
        lc2d_wpack<<<900, 256, 0, stream>>>(w, bias, wp);
        lc2d_main<<<3600, 256, 0, stream>>>(x, wp, out);
    } else {
        lc2d_fb<<<3600, 256, 0, stream>>>(x, w, bias, out);
    }
}

// Round 15
// 75.952 us; speedup vs baseline: 1.0642x; 1.0050x over previous
//
#include <hip/hip_runtime.h>
#include <hip/hip_bf16.h>

// Locally-connected 2D: out[b,o,y,x] = sum_{c,kh,kw} x[b,c,y+kh,x+kw] * W[y,x,o,c*25+kh*5+kw] + b[y,x,o]
// x: [128,3,64,64] f32, W: [60,60,32,75] f32, bias: [60,60,32] f32, out: [128,32,60,60] f32.
//
// 1) wpack (verified r13): W (+bias) -> Wp[pos][o][128] bf16 in EXACT MFMA B-fragment
//    order: k' = cm*8 + w (cm=c*5+kh), window [xi,xi+5) holds W (xi=pos%4 baked via
//    funnel shift), slot 120 = bias (consumed by one-hot A=1.0).
// 2) main v3 (r15): r14 + __builtin_amdgcn_sched_barrier(0) after the load block.
//    r14's VGPR=28 proved the compiler sank all 30 "up-front" loads back to their
//    uses (2 in flight/wave -> 1.6 TB/s latency wall). The fence forces ~30 live
//    load destinations per lane -> 30 outstanding VMEM ops/wave.

#define RY 60
#define RX 60
#define OC 32
#define BATCH 128
#define CIN 3
#define HW 64
#define NPOS 3600
#define KPACK 128

typedef __attribute__((ext_vector_type(8))) short short8;
typedef __attribute__((ext_vector_type(4))) float f32x4;
typedef unsigned long long ull;

__device__ __forceinline__ ushort bf16u(float f) {
    __hip_bfloat16 h = __float2bfloat16(f);
    return *reinterpret_cast<ushort*>(&h);
}
__device__ __forceinline__ unsigned pk2(float a, float b) {
    return (unsigned)bf16u(a) | ((unsigned)bf16u(b) << 16);
}
__device__ __forceinline__ int swz900(int id) {   // bijective XCD chunking for 900
    const int xcd = id & 7, ii = id >> 3;
    return (xcd < 4 ? xcd * 113 : 452 + (xcd - 4) * 112) + ii;
}

// ---------------- prepass: W + bias -> packed bf16 fragments ----------------
__global__ __launch_bounds__(256, 4) void lc2d_wpack(
    const float* __restrict__ w, const float* __restrict__ bias,
    ushort* __restrict__ wp)
{
    __shared__ __align__(16) float wlds[9600 + 128];   // 4 positions x 2400 f32

    const int G   = swz900(blockIdx.x);
    const int tid = threadIdx.x;
    const int lane = tid & 63, wid = tid >> 6;

    {   // async DMA: 38.4KB contiguous W for positions 4G..4G+4
        const float* gW = w + (size_t)G * 4 * (OC * 75);
        for (int j = wid; j < 38; j += 4) {
            const int chunk0 = j * 64;
            int ci = chunk0 + lane;
            if (ci > 2399) ci = 2399;
            __builtin_amdgcn_global_load_lds(
                (const __attribute__((address_space(1))) unsigned*)(gW + ci * 4),
                (__attribute__((address_space(3))) unsigned*)&wlds[chunk0 * 4],
                16, 0, 0);
        }
    }

    const int xi = tid >> 6, o = (tid >> 1) & 31, half = tid & 1;
    const float bv = bias[(size_t)(G * 4 + xi) * OC + o];
    __syncthreads();

    const float* src = &wlds[xi * 2400 + o * 75];
    const int s = xi * 16;
    unsigned wd[32];
    #pragma unroll
    for (int i = 0; i < 32; ++i) wd[i] = 0u;

    #pragma unroll
    for (int cc = 0; cc < 8; ++cc) {
        const int cm = half * 8 + cc;
        if (cm < 15) {
            const float* sp = src + cm * 5;
            const ushort h0 = bf16u(sp[0]), h1 = bf16u(sp[1]), h2 = bf16u(sp[2]),
                         h3 = bf16u(sp[3]), h4 = bf16u(sp[4]);
            const ull lo = (ull)h0 | ((ull)h1 << 16) | ((ull)h2 << 32) | ((ull)h3 << 48);
            const ull hi = (ull)h4;
            const ull rlo = lo << s;
            const ull rhi = (hi << s) | (s ? (lo >> (64 - s)) : 0ull);
            wd[cc * 4 + 0] = (unsigned)rlo;
            wd[cc * 4 + 1] = (unsigned)(rlo >> 32);
            wd[cc * 4 + 2] = (unsigned)rhi;
            wd[cc * 4 + 3] = (unsigned)(rhi >> 32);
        } else {
            wd[cc * 4 + 0] = (unsigned)bf16u(bv);      // k'=120 slot = bias
        }
    }
    ushort* dst = wp + ((size_t)(G * 4 + xi) * OC + o) * KPACK + half * 64;
    #pragma unroll
    for (int q = 0; q < 8; ++q)
        *reinterpret_cast<uint4*>(dst + q * 8) =
            make_uint4(wd[q * 4], wd[q * 4 + 1], wd[q * 4 + 2], wd[q * 4 + 3]);
}

// ---------------- main v3: pinned-ILP fused GEMM ----------------
__global__ __launch_bounds__(256, 3) void lc2d_main(
    const float* __restrict__ x, const ushort* __restrict__ wp,
    float* __restrict__ out)
{
    const int id  = blockIdx.x;
    const int lin = (id & 7) * 450 + (id >> 3);   // same-XCD runs; bs fastest
    const int bs  = lin & 3;
    const int G   = lin >> 2;                     // [0,900)
    const int y   = G / 15;
    const int x0  = (G - y * 15) * 4;
    const int pos0 = y * RX + x0;                 // %4 == 0 -> 16B-aligned stores

    const int lane = threadIdx.x & 63, wid = threadIdx.x >> 6;
    const int lrow = lane & 15, lgrp = lane >> 4;
    const int mt = wid >> 1, nt = wid & 1;
    const int bbase = bs * 32 + mt * 16;
    const int o = nt * 16 + lrow;
    const int b = bbase + lrow;

    // ---- issue ALL A loads (14 independent f32x4) ----
    float4 av[4][2];
    #pragma unroll
    for (int ks = 0; ks < 4; ++ks) {
        const int cm = ks * 4 + lgrp;
        if (cm < 15) {
            const int c = cm / 5, kh = cm - c * 5;
            const float* src = x + (size_t)((b * CIN + c) * HW + (y + kh)) * HW + x0;
            av[ks][0] = *(const float4*)(src);
            av[ks][1] = *(const float4*)(src + 4);
        }
    }
    // ---- issue ALL B loads (16 independent short8, MFMA-ready) ----
    short8 bfr[4][4];   // [xi][ks]
    #pragma unroll
    for (int xi = 0; xi < 4; ++xi) {
        const ushort* wb = wp + ((size_t)(4 * G + xi) * OC + o) * KPACK + lgrp * 8;
        #pragma unroll
        for (int ks = 0; ks < 4; ++ks)
            bfr[xi][ks] = *(const short8*)(wb + ks * 32);
    }

    // ---- FENCE: nothing crosses; loads stay issued, destinations stay live ----
    __builtin_amdgcn_sched_barrier(0);

    // ---- pack A (VALU overlaps load returns); cm==15 -> one-hot 1.0 @ k'=120 ----
    short8 af[4];
    #pragma unroll
    for (int ks = 0; ks < 4; ++ks) {
        const int cm = ks * 4 + lgrp;
        union { unsigned u[4]; short8 s8; } cv;
        if (cm < 15) {
            cv.u[0] = pk2(av[ks][0].x, av[ks][0].y); cv.u[1] = pk2(av[ks][0].z, av[ks][0].w);
            cv.u[2] = pk2(av[ks][1].x, av[ks][1].y); cv.u[3] = pk2(av[ks][1].z, av[ks][1].w);
        } else {
            cv.u[0] = 0x3f80u; cv.u[1] = 0u; cv.u[2] = 0u; cv.u[3] = 0u;
        }
        af[ks] = cv.s8;
    }

    // ---- 16 MFMA ----
    f32x4 accx[4];
    #pragma unroll
    for (int xi = 0; xi < 4; ++xi) accx[xi] = (f32x4){0.f, 0.f, 0.f, 0.f};
    #pragma unroll
    for (int xi = 0; xi < 4; ++xi)
        #pragma unroll
        for (int ks = 0; ks < 4; ++ks)
            accx[xi] = __builtin_amdgcn_mfma_f32_16x16x32_bf16(af[ks], bfr[xi][ks], accx[xi], 0, 0, 0);

    // ---- store: per (b,o) one aligned float4 of the 4 consecutive x ----
    #pragma unroll
    for (int r = 0; r < 4; ++r) {
        const int bg = bbase + lgrp * 4 + r;
        f32x4 v = (f32x4){accx[0][r], accx[1][r], accx[2][r], accx[3][r]};
        *reinterpret_cast<f32x4*>(out + (size_t)(bg * OC + o) * NPOS + pos0) = v;
    }
}

// ---------------- fallback (round-10 fused, no workspace) ----------------
__global__ __launch_bounds__(256, 4) void lc2d_fb(
    const float* __restrict__ x, const float* __restrict__ w,
    const float* __restrict__ bias, float* __restrict__ out)
{
    __shared__ __align__(16) float wlds[4 * 2400 + 128];
    const int tid = threadIdx.x;
    const int id  = blockIdx.x;
    const int lin = (id & 7) * 450 + (id >> 3);
    const int bs  = lin & 3;
    const int pg  = lin >> 2;
    const int y   = pg / 15;
    const int x0  = (pg - y * 15) * 4;
    const int pos0 = y * RX + x0;
    const int lane = tid & 63, wid = tid >> 6;
    const int lrow = lane & 15, lgrp = lane >> 4;
    const int mt = wid >> 1, nt = wid & 1;
    const int bbase = bs * 32 + mt * 16;
    const int o = nt * 16 + lrow;

    float4 av[4][2];
    #pragma unroll
    for (int ks = 0; ks < 4; ++ks) {
        const int cm = ks * 4 + lgrp;
        if (cm < 15) {
            const int c = cm / 5, kh = cm - c * 5;
            const int b = bbase + lrow;
            const float* src = x + (size_t)((b * CIN + c) * HW + (y + kh)) * HW + x0;
            av[ks][0] = *(const float4*)(src);
            av[ks][1] = *(const float4*)(src + 4);
        }
    }
    {
        const float* gW = w + (size_t)pos0 * 2400;
        for (int j = wid; j < 38; j += 4) {
            const int chunk0 = j * 64;
            int ci = chunk0 + lane;
            if (ci > 2399) ci = 2399;
            __builtin_amdgcn_global_load_lds(
                (const __attribute__((address_space(1))) unsigned*)(gW + ci * 4),
                (__attribute__((address_space(3))) unsigned*)&wlds[chunk0 * 4],
                16, 0, 0);
        }
    }
    float bv[4];
    #pragma unroll
    for (int xi = 0; xi < 4; ++xi) bv[xi] = bias[(size_t)(pos0 + xi) * OC + o];

    short8 af[4];
    #pragma unroll
    for (int ks = 0; ks < 4; ++ks) {
        const int cm = ks * 4 + lgrp;
        union { unsigned u[4]; short8 s8; } cv;
        if (cm < 15) {
            cv.u[0] = pk2(av[ks][0].x, av[ks][0].y); cv.u[1] = pk2(av[ks][0].z, av[ks][0].w);
            cv.u[2] = pk2(av[ks][1].x, av[ks][1].y); cv.u[3] = pk2(av[ks][1].z, av[ks][1].w);
        } else { cv.u[0] = cv.u[1] = cv.u[2] = cv.u[3] = 0u; }
        af[ks] = cv.s8;
    }
    __syncthreads();

    f32x4 accx[4];
    #pragma unroll
    for (int xi = 0; xi < 4; ++xi) accx[xi] = (f32x4){0.f, 0.f, 0.f, 0.f};
    const int wbase = o * 75;
    #pragma unroll
    for (int ks = 0; ks < 4; ++ks) {
        const int cm = ks * 4 + lgrp;
        const int soff = wbase + cm * 5;
        #pragma unroll
        for (int xi = 0; xi < 4; ++xi) {
            const float* s = &wlds[xi * 2400 + soff];
            const ushort h[5] = {bf16u(s[0]), bf16u(s[1]), bf16u(s[2]), bf16u(s[3]), bf16u(s[4])};
            unsigned wd[4] = {0u, 0u, 0u, 0u};
            #pragma unroll
            for (int kw = 0; kw < 5; ++kw) {
                const int ws = xi + kw;
                wd[ws >> 1] |= (unsigned)h[kw] << ((ws & 1) * 16);
            }
            union { unsigned u[4]; short8 s8; } cv;
            cv.u[0] = wd[0]; cv.u[1] = wd[1]; cv.u[2] = wd[2]; cv.u[3] = wd[3];
            accx[xi] = __builtin_amdgcn_mfma_f32_16x16x32_bf16(af[ks], cv.s8, accx[xi], 0, 0, 0);
        }
    }
    #pragma unroll
    for (int r = 0; r < 4; ++r) {
        const int bg = bbase + lgrp * 4 + r;
        float4 v;
        v.x = accx[0][r] + bv[0]; v.y = accx[1][r] + bv[1];
        v.z = accx[2][r] + bv[2]; v.w = accx[3][r] + bv[3];
        *(float4*)(out + (size_t)(bg * OC + o) * (RY * RX) + pos0) = v;
    }
}

extern "C" void kernel_launch(void* const* d_in, const int* in_sizes, int n_in,
                              void* d_out, int out_size, void* d_ws, size_t ws_size,
                              hipStream_t stream) {
    const float* x    = (const float*)d_in[0];
    const float* w    = (const float*)d_in[1];
    const float* bias = (const float*)d_in[2];
    float* out        = (float*)d_out;

    const size_t wp_bytes = (size_t)NPOS * OC * KPACK * sizeof(ushort);  // 29.5 MB
    if (ws_size >= wp_bytes) {
        ushort* wp = (ushort*)d_ws;
        lc2d_wpack<<<900, 256, 0, stream>>>(w, bias, wp);
        lc2d_main<<<3600, 256, 0, stream>>>(x, wp, out);
    } else {
        lc2d_fb<<<3600, 256, 0, stream>>>(x, w, bias, out);
    }
}